// Round 4
// baseline (255.332 us; speedup 1.0000x reference)
//
#include <hip/hip_runtime.h>

#define DIM 64
#define NW 8188          // number of output windows
#define OUT_STRIDE 4160  // 64 + 64*64 floats per output row
#define NCHUNK 32        // groups per scan chunk

// ---------------------------------------------------------------------------
// Wave-autonomous sweep: ONE WAVE per group (4 waves/block, private LDS
// slices, no __syncthreads). Each lane holds an 8x8 register tile of the
// 64x64 level-2 accumulator (lane>>3 -> a-octet, lane&7 -> b-octet).
// EMIT=0: write group totals T[g].  EMIT=1: seed from scanned prefix
// (T[g] intra-chunk prefix + C[g/NCHUNK] chunk offset incl. base), emit
// one 4160-float output row per window.
// ---------------------------------------------------------------------------
template <int WPW, int NGv, bool EMIT>
__global__ __launch_bounds__(256) void k_sweep(const float* __restrict__ x,
                                               float* __restrict__ T,
                                               const float* __restrict__ C,
                                               float* __restrict__ out) {
  __shared__ float sm[4][32][DIM];  // 32 KB (8 KB per wave)
  __shared__ float sd[4][32][DIM];  // 32 KB
  const int tid = threadIdx.x, wid = tid >> 6, lane = tid & 63;
  const int g = blockIdx.x * 4 + wid;
  if (g >= NGv) return;
  float(*SM)[DIM] = sm[wid];
  float(*SD)[DIM] = sd[wid];
  const int wcount = min(WPW, NW - g * WPW);
  const int t0 = 128 + 32 * WPW * g;
  const int A8 = (lane >> 3) << 3, B8 = (lane & 7) << 3;
  const int srow = lane >> 4;         // staging row-within-quad 0..3
  const int scol = (lane & 15) << 2;  // staging col quad
  const float4 x0q = *(const float4*)&x[scol];

  float4 acc[8][2];
  if (EMIT) {
    const float* Tg = T + (size_t)g * 4096;
    const float* Cc = C + (size_t)(g / NCHUNK) * 4096;
#pragma unroll
    for (int i = 0; i < 8; ++i) {
#pragma unroll
      for (int q = 0; q < 2; ++q) {
        const float4 tv = *(const float4*)&Tg[(A8 + i) * DIM + B8 + 4 * q];
        const float4 cv = *(const float4*)&Cc[(A8 + i) * DIM + B8 + 4 * q];
        acc[i][q] = make_float4(tv.x + cv.x, tv.y + cv.y, tv.z + cv.z, tv.w + cv.w);
      }
    }
  } else {
#pragma unroll
    for (int i = 0; i < 8; ++i)
#pragma unroll
      for (int q = 0; q < 2; ++q) acc[i][q] = make_float4(0.f, 0.f, 0.f, 0.f);
  }

  // register prefetch of one window's raw rows (wave-contiguous 1KB loads)
  float4 rc[8], rp[8];
  auto issue = [&](int tw) {
#pragma unroll
    for (int j = 0; j < 8; ++j) {
      const size_t r = (size_t)(tw + 4 * j + srow) * DIM + scol;
      rc[j] = *(const float4*)&x[r];
      rp[j] = *(const float4*)&x[r - DIM];
    }
  };
  issue(t0);

  for (int w = 0; w < wcount; ++w) {
    // transform prefetched regs -> m,d and write own LDS slice (no barrier:
    // same-wave ds ordering is handled by the compiler's lgkmcnt)
#pragma unroll
    for (int j = 0; j < 8; ++j) {
      const int rr = 4 * j + srow;
      float4 m, d;
      m.x = 0.5f * (rc[j].x + rp[j].x) - x0q.x;
      m.y = 0.5f * (rc[j].y + rp[j].y) - x0q.y;
      m.z = 0.5f * (rc[j].z + rp[j].z) - x0q.z;
      m.w = 0.5f * (rc[j].w + rp[j].w) - x0q.w;
      d.x = rc[j].x - rp[j].x;
      d.y = rc[j].y - rp[j].y;
      d.z = rc[j].z - rp[j].z;
      d.w = rc[j].w - rp[j].w;
      *(float4*)&SM[rr][scol] = m;
      *(float4*)&SD[rr][scol] = d;
    }
    if (w + 1 < wcount) issue(t0 + 32 * (w + 1));  // in flight during compute

#pragma unroll 4
    for (int ti = 0; ti < 32; ++ti) {
      const float4 m0 = *(const float4*)&SM[ti][A8];
      const float4 m1 = *(const float4*)&SM[ti][A8 + 4];
      const float4 d0 = *(const float4*)&SD[ti][B8];
      const float4 d1 = *(const float4*)&SD[ti][B8 + 4];
      const float ma[8] = {m0.x, m0.y, m0.z, m0.w, m1.x, m1.y, m1.z, m1.w};
#pragma unroll
      for (int i = 0; i < 8; ++i) {
        acc[i][0].x += ma[i] * d0.x;
        acc[i][0].y += ma[i] * d0.y;
        acc[i][0].z += ma[i] * d0.z;
        acc[i][0].w += ma[i] * d0.w;
        acc[i][1].x += ma[i] * d1.x;
        acc[i][1].y += ma[i] * d1.y;
        acc[i][1].z += ma[i] * d1.z;
        acc[i][1].w += ma[i] * d1.w;
      }
    }

    if (EMIT) {
      const int j = g * WPW + w;
      float* row = out + (size_t)j * OUT_STRIDE;
      // level 1: x_n - x_0 == m[31] + 0.5*d[31] (from own LDS slice)
      row[lane] = SM[31][lane] + 0.5f * SD[31][lane];
      float* r2 = row + 64;
#pragma unroll
      for (int i = 0; i < 8; ++i) {
        *(float4*)&r2[(A8 + i) * DIM + B8] = acc[i][0];
        *(float4*)&r2[(A8 + i) * DIM + B8 + 4] = acc[i][1];
      }
    }
  }
  if (!EMIT) {
    float* Tg = T + (size_t)g * 4096;
#pragma unroll
    for (int i = 0; i < 8; ++i) {
      *(float4*)&Tg[(A8 + i) * DIM + B8] = acc[i][0];
      *(float4*)&Tg[(A8 + i) * DIM + B8 + 4] = acc[i][1];
    }
  }
}

// ---------------------------------------------------------------------------
// Intra-chunk exclusive scan of group totals, in place; C[c] = chunk total.
// grid = NC*16 blocks (16 blocks cover one chunk's 4096 elements).
// ---------------------------------------------------------------------------
template <int NGv>
__global__ __launch_bounds__(256) void k_scanA(float* __restrict__ T,
                                               float* __restrict__ C) {
  const int c = blockIdx.x >> 4;
  const int e = (blockIdx.x & 15) * 256 + threadIdx.x;
  const int gbeg = c * NCHUNK, gend = min(gbeg + NCHUNK, NGv);
  float acc = 0.f;
  for (int g = gbeg; g < gend; ++g) {
    const size_t idx = (size_t)g * 4096 + e;
    const float t = T[idx];
    T[idx] = acc;
    acc += t;
  }
  C[(size_t)c * 4096 + e] = acc;
}

// ---------------------------------------------------------------------------
// Chunk-total exclusive scan, in place, seeded with the level-2 signature of
// x[:128] (fused prefix-base). 16 blocks x 256 threads = 4096 elements.
// ---------------------------------------------------------------------------
template <int NCv>
__global__ __launch_bounds__(256) void k_scanB(const float* __restrict__ x,
                                               float* __restrict__ C) {
  __shared__ float sx[128][DIM];  // 32 KB
  const int tid = threadIdx.x;
  for (int f = tid; f < 128 * (DIM / 4); f += 256) {
    const int r = f >> 4, c4 = (f & 15) << 2;
    *(float4*)&sx[r][c4] = *(const float4*)&x[(size_t)r * DIM + c4];
  }
  __syncthreads();
  const int e = blockIdx.x * 256 + tid;
  const int a = e >> 6, b = e & 63;
  float acc = 0.f;
  for (int t = 1; t < 128; ++t)
    acc += (0.5f * (sx[t][a] + sx[t - 1][a]) - sx[0][a]) *
           (sx[t][b] - sx[t - 1][b]);
  for (int c = 0; c < NCv; ++c) {
    const size_t idx = (size_t)c * 4096 + e;
    const float t = C[idx];
    C[idx] = acc;
    acc += t;
  }
}

extern "C" void kernel_launch(void* const* d_in, const int* in_sizes, int n_in,
                              void* d_out, int out_size, void* d_ws, size_t ws_size,
                              hipStream_t stream) {
  const float* x = (const float*)d_in[0];
  float* out = (float*)d_out;
  // Primary: WPW=4 -> NG=2047 (NW = 4*2047 exactly), NC=64, grid 512 blocks.
  const size_t need4 = (size_t)(2047 + 64) * 4096 * sizeof(float);
  if (ws_size >= need4) {
    float* T = (float*)d_ws;
    float* C = T + (size_t)2047 * 4096;
    k_sweep<4, 2047, false><<<512, 256, 0, stream>>>(x, T, C, nullptr);
    k_scanA<2047><<<64 * 16, 256, 0, stream>>>(T, C);
    k_scanB<64><<<16, 256, 0, stream>>>(x, C);
    k_sweep<4, 2047, true><<<512, 256, 0, stream>>>(x, T, C, out);
  } else {
    // Fallback for small workspace: WPW=8 -> NG=1024, NC=32, grid 256.
    float* T = (float*)d_ws;
    float* C = T + (size_t)1024 * 4096;
    k_sweep<8, 1024, false><<<256, 256, 0, stream>>>(x, T, C, nullptr);
    k_scanA<1024><<<32 * 16, 256, 0, stream>>>(T, C);
    k_scanB<32><<<16, 256, 0, stream>>>(x, C);
    k_sweep<8, 1024, true><<<256, 256, 0, stream>>>(x, T, C, out);
  }
}